// Round 1
// 333.818 us; speedup vs baseline: 1.0077x; 1.0077x over previous
//
#include <hip/hip_runtime.h>

// PartPP: per (frame, part, channel) segment mean+max pooling.
// x: (32, 256, 30, 16, 16) fp32 ; labels: (32, 30, 16, 16) int ; out: (32, 256, 30, 16) fp32
//
// Memory-bound (~268 MB traffic, floor ~43 us).
// R3 strategy: (1) 16-channel blocks -> 20.1 KB LDS -> 8 blocks/CU (32 waves = max
// occupancy, 2x latency-hiding depth vs R2); (2) part buckets 4-aligned in the
// prefix scan, pads filled with -100.0 (neutral for the fmaxf(mx,-100) semantics,
// sum corrected by +100*npad) -> branch-free float4 reduce, ~4x fewer LDS instrs;
// (3) one (channel, part) per thread -> half the serial trip count / divergence.

#define C_DIM 256
#define S_DIM 30
#define P_NUM 16
#define HW 256
#define CH_PER_BLK 16
#define TS 304   // floats per LDS row: >=304 (worst-case 4-aligned buckets), 16B-aligned rows

__global__ __launch_bounds__(256, 8)
void partpp_pool_kernel(const float* __restrict__ x,
                        const int* __restrict__ labels,
                        float* __restrict__ out) {
    __shared__ float tile[CH_PER_BLK * TS];     // 19456 B
    __shared__ unsigned short rank[HW];         // 512 B  (max rank 303 fits u16)
    __shared__ int counts[P_NUM], cursor[P_NUM], offs[P_NUM + 1];

    const int t   = threadIdx.x;
    const int b   = blockIdx.x;
    const int f   = b >> 4;                // frame id 0..959 (f = n*30 + s)
    const int g   = b & 15;                // channel group
    const int ch0 = g * CH_PER_BLK;
    const int n   = f / S_DIM;
    const int s   = f - n * S_DIM;

    // ---- issue all global loads up front (overlap HBM latency with metadata) ----
    const int lab = labels[f * HW + t];    // 1KB coalesced, L2-resident across groups

    const size_t xbase = ((size_t)(n * C_DIM + ch0) * S_DIM + s) * HW;
    const int col = t & 63;                // float4 column 0..63
    float4 v[4];
    #pragma unroll
    for (int j = 0; j < 4; ++j) {
        const int row = j * 4 + (t >> 6);  // per wave: one contiguous 1KB row segment
        v[j] = *(const float4*)(x + xbase + (size_t)row * (S_DIM * HW) + col * 4);
    }

    // ---- metadata: histogram + 4-aligned scan + rank ----
    if (t < P_NUM) { counts[t] = 0; cursor[t] = 0; }
    __syncthreads();
    atomicAdd(&counts[lab], 1);
    __syncthreads();
    if (t == 0) {
        int acc = 0;
        #pragma unroll
        for (int p = 0; p < P_NUM; ++p) {
            offs[p] = acc;
            acc += (counts[p] + 3) & ~3;   // bucket length rounded to x4
        }
        offs[P_NUM] = acc;                 // <= 304
    }
    __syncthreads();
    rank[t] = (unsigned short)(offs[lab] + atomicAdd(&cursor[lab], 1));
    __syncthreads();

    // ---- stage: scatter x into bucket-sorted LDS layout ----
    const ushort4 rk = *(const ushort4*)&rank[col * 4];   // 8B-aligned LDS read
    #pragma unroll
    for (int j = 0; j < 4; ++j) {
        const int row = j * 4 + (t >> 6);
        float* rp = &tile[row * TS];
        rp[rk.x] = v[j].x;
        rp[rk.y] = v[j].y;
        rp[rk.z] = v[j].z;
        rp[rk.w] = v[j].w;
    }
    __syncthreads();

    // ---- reduce: thread = (channel, part); branch-free float4 loop ----
    const int ch = t >> 4;     // 0..15
    const int p  = t & 15;     // 0..15
    float* rowp = &tile[ch * TS];
    const int jb   = offs[p];
    const int cnt  = counts[p];
    const int len4 = (cnt + 3) & ~3;

    // fill this bucket's pad slots with -100 (read back only by this same thread,
    // so no extra barrier; -100 is neutral: max uses fmaxf(mx,-100) anyway, and
    // the sum is corrected below)
    for (int k = jb + cnt; k < jb + len4; ++k) rowp[k] = -100.0f;

    float sum = 0.0f;
    float mx  = -3.0e38f;
    const float4* rp4 = (const float4*)(rowp + jb);   // jb is x4 -> 16B aligned
    const int n4 = len4 >> 2;
    for (int q = 0; q < n4; ++q) {
        const float4 vv = rp4[q];                     // independent ds_read_b128
        sum += vv.x + vv.y + vv.z + vv.w;
        mx = fmaxf(fmaxf(mx, fmaxf(vv.x, vv.y)), fmaxf(vv.z, vv.w));
    }
    sum += 100.0f * (float)(len4 - cnt);              // undo pad contribution

    // torch scatter_reduce amax include_self(-100); empty part -> 0
    const float res = (cnt > 0) ? (sum / (float)cnt + fmaxf(mx, -100.0f)) : 0.0f;

    // out[((n*C + c)*S + s)*P + p]; 16 lanes -> 64B contiguous per channel
    out[((size_t)(n * C_DIM + ch0 + ch) * S_DIM + s) * P_NUM + p] = res;
}

extern "C" void kernel_launch(void* const* d_in, const int* in_sizes, int n_in,
                              void* d_out, int out_size, void* d_ws, size_t ws_size,
                              hipStream_t stream) {
    const float* x      = (const float*)d_in[0];
    const int*   labels = (const int*)d_in[1];
    float*       out    = (float*)d_out;

    // 960 frames x 16 channel-groups
    dim3 grid(960 * 16), block(256);
    hipLaunchKernelGGL(partpp_pool_kernel, grid, block, 0, stream, x, labels, out);
}